// Round 12
// baseline (33.617 us; speedup 1.0000x reference)
//
#include <hip/hip_runtime.h>

#define D     256
#define BATCH 4096
#define NMOM  25   // Taylor terms n = 0..24; tail at |x|<=5.5 is < 3e-7 abs

typedef __attribute__((ext_vector_type(8))) short short8;
typedef __attribute__((ext_vector_type(4))) short short4e;
typedef __attribute__((ext_vector_type(4))) float f32x4;

__constant__ float INVFACT[NMOM] = {
    1.0f, 1.0f, 0.5f,
    1.6666666666666666e-01f, 4.1666666666666664e-02f, 8.3333333333333332e-03f,
    1.3888888888888889e-03f, 1.9841269841269841e-04f, 2.4801587301587302e-05f,
    2.7557319223985893e-06f, 2.7557319223985888e-07f, 2.5052108385441720e-08f,
    2.0876756987868100e-09f, 1.6059043836821613e-10f, 1.1470745597729725e-11f,
    7.6471637318198164e-13f, 4.7794773323873853e-14f, 2.8114572543455206e-15f,
    1.5619206968586225e-16f, 8.2206352466243295e-18f, 4.1103176233121648e-19f,
    1.9572941063391263e-20f, 8.8967913924505741e-22f, 3.8681701706306843e-23f,
    1.6117375710961184e-24f };

// ---------------------------------------------------------------------------
// f32 -> bf16 hi + bf16 lo (truncation split). Product error ~2^-16 relative.
// ---------------------------------------------------------------------------
__device__ __forceinline__ void split1(float v, short& h, short& l) {
    unsigned int b = __float_as_uint(v);
    h = (short)(b >> 16);
    float lo = v - __uint_as_float(b & 0xFFFF0000u);
    l = (short)(__float_as_uint(lo) >> 16);
}

__device__ __forceinline__ void split8(const float4 f0, const float4 f1,
                                       short8& h, short8& l) {
    float v[8] = {f0.x, f0.y, f0.z, f0.w, f1.x, f1.y, f1.z, f1.w};
#pragma unroll
    for (int i = 0; i < 8; ++i) { short hh, ll; split1(v[i], hh, ll); h[i] = hh; l[i] = ll; }
}

// ---------------------------------------------------------------------------
// QKV GEMM — EXACT round-3/8/11 hot loop (validated 4x):
// in-kernel split staging, 64x64 tile, 4 waves 2x2, wave tile 32x32,
// 16x16x32 bf16, 3-MFMA split, padded [.][40] LDS rows (conflict-free),
// loads -> barrier -> ds_write -> barrier -> MFMA. Grid (64,4,3) = 768.
// ---------------------------------------------------------------------------
__global__ __launch_bounds__(256) void qkv_kernel(
    const float* __restrict__ x,
    const float* __restrict__ Wq, const float* __restrict__ bq,
    const float* __restrict__ Wk, const float* __restrict__ bk,
    const float* __restrict__ Wv, const float* __restrict__ bv,
    float* __restrict__ Qo, float* __restrict__ Ko, float* __restrict__ Vo) {
    __shared__ short Ah[64][40], Al[64][40];
    __shared__ short Bh[64][40], Bl[64][40];

    const int z = blockIdx.z;
    const float* W    = (z == 0) ? Wq : (z == 1) ? Wk : Wv;
    const float* bias = (z == 0) ? bq : (z == 1) ? bk : bv;
    float*       C    = (z == 0) ? Qo : (z == 1) ? Ko : Vo;

    const int b0 = blockIdx.x * 64, n0 = blockIdx.y * 64;
    const int tid  = threadIdx.x;
    const int lane = tid & 63;
    const int wave = tid >> 6;
    const int wm   = wave >> 1;
    const int wn   = wave & 1;
    const int fr   = lane & 15;
    const int fq   = lane >> 4;
    const int sr   = tid >> 2;          // staging row 0..63
    const int sq   = tid & 3;           // staging k-quarter (8 f32)

    f32x4 acc[2][2] = {};

    const float* aBase = x + (size_t)(b0 + sr) * D + sq * 8;
    const float* wBase = W + (size_t)(n0 + sr) * D + sq * 8;

    for (int k0 = 0; k0 < D; k0 += 32) {
        float4 a0 = *(const float4*)(aBase + k0);
        float4 a1 = *(const float4*)(aBase + k0 + 4);
        float4 w0 = *(const float4*)(wBase + k0);
        float4 w1 = *(const float4*)(wBase + k0 + 4);

        __syncthreads();   // previous tile fully consumed

        short8 h, l;
        split8(a0, a1, h, l);
        *(short8*)&Ah[sr][sq * 8] = h;
        *(short8*)&Al[sr][sq * 8] = l;
        split8(w0, w1, h, l);
        *(short8*)&Bh[sr][sq * 8] = h;
        *(short8*)&Bl[sr][sq * 8] = l;

        __syncthreads();

        short8 arh[2], arl[2], brh[2], brl[2];
#pragma unroll
        for (int mi = 0; mi < 2; ++mi) {
            const int r = wm * 32 + mi * 16 + fr;
            arh[mi] = *(const short8*)&Ah[r][fq * 8];
            arl[mi] = *(const short8*)&Al[r][fq * 8];
        }
#pragma unroll
        for (int ni = 0; ni < 2; ++ni) {
            const int r = wn * 32 + ni * 16 + fr;
            brh[ni] = *(const short8*)&Bh[r][fq * 8];
            brl[ni] = *(const short8*)&Bl[r][fq * 8];
        }
#pragma unroll
        for (int mi = 0; mi < 2; ++mi)
#pragma unroll
            for (int ni = 0; ni < 2; ++ni) {
                acc[mi][ni] = __builtin_amdgcn_mfma_f32_16x16x32_bf16(
                    arh[mi], brl[ni], acc[mi][ni], 0, 0, 0);
                acc[mi][ni] = __builtin_amdgcn_mfma_f32_16x16x32_bf16(
                    arl[mi], brh[ni], acc[mi][ni], 0, 0, 0);
                acc[mi][ni] = __builtin_amdgcn_mfma_f32_16x16x32_bf16(
                    arh[mi], brh[ni], acc[mi][ni], 0, 0, 0);
            }
    }

    // C/D layout 16x16x32: col = lane&15, row = (lane>>4)*4 + reg
#pragma unroll
    for (int ni = 0; ni < 2; ++ni) {
        const int col = n0 + wn * 32 + ni * 16 + fr;
        const float bvv = bias[col];
#pragma unroll
        for (int mi = 0; mi < 2; ++mi) {
            const int rbase = b0 + wm * 32 + mi * 16 + fq * 4;
#pragma unroll
            for (int r = 0; r < 4; ++r)
                C[(size_t)(rbase + r) * D + col] = acc[mi][ni][r] + bvv;
        }
    }
}

// ---------------------------------------------------------------------------
// Moment-based attention — barrier-free wave-per-sample (structure validated
// R9; banking from R3). 4 waves/block, wave-private LDS slices, scalar
// [65][2] layout (stride 130 words = 2 mod 32 -> free 2-way; the float2
// [66][2] variant is 4-way conflicted, R8/R9 regression).
//   S_n = sum_j k_j^n, M_n = sum_j k_j^n v_j; out_i = num(q_i)/den(q_i);
// k centered per-sample (softmax shift-invariant) => |q*k| <~ 5.5.
// Same-wave DS ops execute in order -> no barriers needed (R9 precedent).
// Reduce uses 4 accumulators (chain depth 8, was 32). Output pre-split
// (bf16 hi/lo) for oproj. attn_w is filled by oproj's epilogue instead.
// ---------------------------------------------------------------------------
__device__ __forceinline__ void attn_wave(
    int s, int l,
    const float* __restrict__ Q, const float* __restrict__ K,
    const float* __restrict__ V,
    float (*part)[65][2], float (*coef)[2],
    short* __restrict__ Abh, short* __restrict__ Abl) {
    const int c    = l & 31;
    const int half = l >> 5;

    float4 k4 = *(const float4*)&K[(size_t)s * D + 4 * l];
    float4 v4 = *(const float4*)&V[(size_t)s * D + 4 * l];
    float4 q4 = *(const float4*)&Q[(size_t)s * D + 4 * l];  // early issue

    float ksum = (k4.x + k4.y) + (k4.z + k4.w);
#pragma unroll
    for (int off = 32; off; off >>= 1) ksum += __shfl_xor(ksum, off);
    const float kbar = ksum * (1.0f / 256.0f);
    float ks[4] = {k4.x - kbar, k4.y - kbar, k4.z - kbar, k4.w - kbar};
    float vs[4] = {v4.x, v4.y, v4.z, v4.w};

    float p[4] = {1.f, 1.f, 1.f, 1.f};
#pragma unroll
    for (int pass = 0; pass < 2; ++pass) {
        const int nlo  = pass ? 16 : 0;
        const int ncnt = pass ? (NMOM - 16) : 16;   // 16 or 9

        for (int nn = 0; nn < ncnt; ++nn) {
            if (nlo + nn > 0) {
#pragma unroll
                for (int u = 0; u < 4; ++u) p[u] *= ks[u];
            }
            float sv = (p[0] + p[1]) + (p[2] + p[3]);
            float mv = fmaf(p[0], vs[0],
                       fmaf(p[1], vs[1],
                       fmaf(p[2], vs[2], p[3] * vs[3])));
            part[nn][l][0] = sv;
            part[nn][l][1] = mv;
        }
        // wave-private slice: same-wave DS ordering makes writes visible

        const int nvals = ncnt * 2;                 // 32 or 18
        float a0 = 0.f, a1 = 0.f, a2 = 0.f, a3 = 0.f;
        if (c < nvals) {
            const int rn = c >> 1, h = c & 1;
            const float* pp = &part[rn][half * 32][h];
#pragma unroll
            for (int t = 0; t < 8; ++t) {
                a0 += pp[2 * t];
                a1 += pp[2 * (t + 8)];
                a2 += pp[2 * (t + 16)];
                a3 += pp[2 * (t + 24)];
            }
        }
        float acc = (a0 + a1) + (a2 + a3);
        acc += __shfl_xor(acc, 32);                 // combine lane halves
        if (half == 0 && c < nvals) {
            const int n = nlo + (c >> 1);
            coef[n][c & 1] = acc * INVFACT[n];
        }
    }

    // Horner evaluation at the 4 q values this lane owns
    float qs[4] = {q4.x, q4.y, q4.z, q4.w};
    float de[4], nu[4];
#pragma unroll
    for (int u = 0; u < 4; ++u) {
        de[u] = coef[NMOM - 1][0];
        nu[u] = coef[NMOM - 1][1];
    }
#pragma unroll
    for (int n = NMOM - 2; n >= 0; --n) {
        const float cs = coef[n][0];
        const float cm = coef[n][1];
#pragma unroll
        for (int u = 0; u < 4; ++u) {
            de[u] = fmaf(de[u], qs[u], cs);
            nu[u] = fmaf(nu[u], qs[u], cm);
        }
    }

    short4e oh, ol;
#pragma unroll
    for (int u = 0; u < 4; ++u) {
        float o = nu[u] * __builtin_amdgcn_rcpf(de[u]);
        short hh, ll; split1(o, hh, ll);
        oh[u] = hh; ol[u] = ll;
    }
    *(short4e*)&Abh[(size_t)s * D + 4 * l] = oh;
    *(short4e*)&Abl[(size_t)s * D + 4 * l] = ol;
}

__global__ __launch_bounds__(256) void attn_kernel(
    const float* __restrict__ Q, const float* __restrict__ K,
    const float* __restrict__ V,
    short* __restrict__ Abh, short* __restrict__ Abl) {
    __shared__ float part[4][16][65][2];   // 33.3 KB, per-wave slices
    __shared__ float coef[4][NMOM][2];
    const int w = threadIdx.x >> 6;
    const int l = threadIdx.x & 63;
    attn_wave(blockIdx.x * 4 + w, l, Q, K, V, part[w], coef[w], Abh, Abl);
}

// ---------------------------------------------------------------------------
// oproj — R8/R11-validated: A pre-split by attn (copy staging), Wo split
// in-kernel, grid (64,4) = 256 blocks. Epilogue also fills the constant
// output attention_weights = 1/256 (softmax rows sum to 1).
// ---------------------------------------------------------------------------
__global__ __launch_bounds__(256) void oproj_kernel(
    const short* __restrict__ AhG, const short* __restrict__ AlG,
    const float* __restrict__ Wo, const float* __restrict__ bo,
    float* __restrict__ C, float* __restrict__ attn_w) {
    __shared__ short Ah[64][40], Al[64][40];
    __shared__ short Bh[64][40], Bl[64][40];

    const int b0 = blockIdx.x * 64, n0 = blockIdx.y * 64;
    const int tid  = threadIdx.x;
    const int lane = tid & 63;
    const int wave = tid >> 6;
    const int wm   = wave >> 1;
    const int wn   = wave & 1;
    const int fr   = lane & 15;
    const int fq   = lane >> 4;
    const int sr   = tid >> 2;
    const int sq   = tid & 3;

    f32x4 acc[2][2] = {};

    const short* aH    = AhG + (size_t)(b0 + sr) * D + sq * 8;
    const short* aL    = AlG + (size_t)(b0 + sr) * D + sq * 8;
    const float* wBase = Wo + (size_t)(n0 + sr) * D + sq * 8;

    for (int k0 = 0; k0 < D; k0 += 32) {
        short8 ah8 = *(const short8*)(aH + k0);
        short8 al8 = *(const short8*)(aL + k0);
        float4 w0  = *(const float4*)(wBase + k0);
        float4 w1  = *(const float4*)(wBase + k0 + 4);

        __syncthreads();   // previous tile fully consumed

        *(short8*)&Ah[sr][sq * 8] = ah8;
        *(short8*)&Al[sr][sq * 8] = al8;
        short8 h, l;
        split8(w0, w1, h, l);
        *(short8*)&Bh[sr][sq * 8] = h;
        *(short8*)&Bl[sr][sq * 8] = l;

        __syncthreads();

        short8 arh[2], arl[2], brh[2], brl[2];
#pragma unroll
        for (int mi = 0; mi < 2; ++mi) {
            const int r = wm * 32 + mi * 16 + fr;
            arh[mi] = *(const short8*)&Ah[r][fq * 8];
            arl[mi] = *(const short8*)&Al[r][fq * 8];
        }
#pragma unroll
        for (int ni = 0; ni < 2; ++ni) {
            const int r = wn * 32 + ni * 16 + fr;
            brh[ni] = *(const short8*)&Bh[r][fq * 8];
            brl[ni] = *(const short8*)&Bl[r][fq * 8];
        }
#pragma unroll
        for (int mi = 0; mi < 2; ++mi)
#pragma unroll
            for (int ni = 0; ni < 2; ++ni) {
                acc[mi][ni] = __builtin_amdgcn_mfma_f32_16x16x32_bf16(
                    arh[mi], brl[ni], acc[mi][ni], 0, 0, 0);
                acc[mi][ni] = __builtin_amdgcn_mfma_f32_16x16x32_bf16(
                    arl[mi], brh[ni], acc[mi][ni], 0, 0, 0);
                acc[mi][ni] = __builtin_amdgcn_mfma_f32_16x16x32_bf16(
                    arh[mi], brh[ni], acc[mi][ni], 0, 0, 0);
            }
    }

#pragma unroll
    for (int ni = 0; ni < 2; ++ni) {
        const int col = n0 + wn * 32 + ni * 16 + fr;
        const float bvv = bo[col];
#pragma unroll
        for (int mi = 0; mi < 2; ++mi) {
            const int rbase = b0 + wm * 32 + mi * 16 + fq * 4;
#pragma unroll
            for (int r = 0; r < 4; ++r)
                C[(size_t)(rbase + r) * D + col] = acc[mi][ni][r] + bvv;
        }
    }

    // attention_weights = 1/256 everywhere (softmax rows sum to 1).
    // 256 blocks x 256 threads x 4 float4 = 4 MB.
    {
        const float4 cw = {1.0f/256.0f, 1.0f/256.0f, 1.0f/256.0f, 1.0f/256.0f};
        float4* dst = (float4*)attn_w;
        const int base = (blockIdx.y * 64 + blockIdx.x) * 256 + tid; // 0..65535
#pragma unroll
        for (int r = 0; r < 4; ++r)
            dst[(size_t)r * 65536 + base] = cw;
    }
}

// ---------------------------------------------------------------------------
extern "C" void kernel_launch(void* const* d_in, const int* in_sizes, int n_in,
                              void* d_out, int out_size, void* d_ws, size_t ws_size,
                              hipStream_t stream) {
    const float* x  = (const float*)d_in[0];
    const float* Wq = (const float*)d_in[1];
    const float* bq = (const float*)d_in[2];
    const float* Wk = (const float*)d_in[3];
    const float* bk = (const float*)d_in[4];
    const float* Wv = (const float*)d_in[5];
    const float* bv = (const float*)d_in[6];
    const float* Wo = (const float*)d_in[7];
    const float* bo = (const float*)d_in[8];

    float* out    = (float*)d_out;
    float* attn_w = out;                       // output 0: [4096,256] = 1/256
    float* out2   = out + (size_t)BATCH * D;   // output 1: [4096,256]

    char* wsp = (char*)d_ws;
    float* Qb  = (float*)(wsp + 0);              // 4 MB
    float* Kb  = (float*)(wsp + (4u << 20));     // 4 MB
    float* Vb  = (float*)(wsp + (8u << 20));     // 4 MB
    short* Abh = (short*)(wsp + (12u << 20));    // 2 MB
    short* Abl = (short*)(wsp + (14u << 20));    // 2 MB

    dim3 gqkv(BATCH / 64, D / 64, 3);
    qkv_kernel<<<gqkv, 256, 0, stream>>>(x, Wq, bq, Wk, bk, Wv, bv, Qb, Kb, Vb);

    attn_kernel<<<BATCH / 4, 256, 0, stream>>>(Qb, Kb, Vb, Abh, Abl);

    dim3 gout(BATCH / 64, D / 64, 1);
    oproj_kernel<<<gout, 256, 0, stream>>>(Abh, Abl, Wo, bo, out2, attn_w);
}